// Round 1
// baseline (1175.370 us; speedup 1.0000x reference)
//
#include <hip/hip_runtime.h>

#define T_  1024
#define B_  8
#define D_  768
#define H_  12
#define HD_ 64
#define BH_ 96
#define M_  8192   // T_*B_

// ---------------------------------------------------------------------------
// Kernel 1: fused QKV projection.  C = X @ W^T + b  (modal split on rows),
// output written in head-major layout [B*H][T][hd].  q scaled by hd^-0.5.
// Tile 64x64, BK=16, 256 threads, 4x4 register blocking.
// ---------------------------------------------------------------------------
__global__ __launch_bounds__(256)
void qkv_proj_kernel(const float* __restrict__ query,
                     const float* __restrict__ keyi,
                     const float* __restrict__ value,
                     const int*   __restrict__ ls_ptr,
                     const float* __restrict__ Wq,  const float* __restrict__ bq,
                     const float* __restrict__ Wk,  const float* __restrict__ bk,
                     const float* __restrict__ Wv,  const float* __restrict__ bv,
                     const float* __restrict__ Wqm, const float* __restrict__ bqm,
                     const float* __restrict__ Wkm, const float* __restrict__ bkm,
                     const float* __restrict__ Wvm, const float* __restrict__ bvm,
                     float* __restrict__ qh, float* __restrict__ kh,
                     float* __restrict__ vh)
{
    const int z  = blockIdx.z;          // 0=q 1=k 2=v
    const int m0 = blockIdx.y * 64;     // row tile origin (t*8+b flat)
    const int n0 = blockIdx.x * 64;     // col tile origin (== head*64)
    const int tid = threadIdx.x;
    const int tr = tid >> 4, tc = tid & 15;
    const int tr4 = tr * 4, tc4 = tc * 4;

    const int  ls_row = ls_ptr[0] * B_;     // modal boundary in flat rows
    const bool modal  = (m0 >= ls_row);     // tile-uniform (4096 is 64-aligned)

    const float* X; const float* W; const float* bias; float* dst;
    if (z == 0)      { X = query; W = modal ? Wqm : Wq; bias = modal ? bqm : bq; dst = qh; }
    else if (z == 1) { X = keyi;  W = modal ? Wkm : Wk; bias = modal ? bkm : bk; dst = kh; }
    else             { X = value; W = modal ? Wvm : Wv; bias = modal ? bvm : bv; dst = vh; }

    __shared__ float As[16][68];   // [k][row]  (transposed, padded)
    __shared__ float Ws[16][68];   // [k][col]

    float acc[4][4] = {};

    const int lr = tid >> 2;          // 0..63 : row (A) / out-col (W)
    const int lk = (tid & 3) * 4;     // k sub-offset

    for (int kt = 0; kt < D_; kt += 16) {
        const float4 av = *reinterpret_cast<const float4*>(
            &X[(size_t)(m0 + lr) * D_ + kt + lk]);
        const float4 wv = *reinterpret_cast<const float4*>(
            &W[(size_t)(n0 + lr) * D_ + kt + lk]);
        __syncthreads();
        As[lk + 0][lr] = av.x; As[lk + 1][lr] = av.y;
        As[lk + 2][lr] = av.z; As[lk + 3][lr] = av.w;
        Ws[lk + 0][lr] = wv.x; Ws[lk + 1][lr] = wv.y;
        Ws[lk + 2][lr] = wv.z; Ws[lk + 3][lr] = wv.w;
        __syncthreads();
        #pragma unroll
        for (int kk = 0; kk < 16; ++kk) {
            const float4 a4 = *reinterpret_cast<const float4*>(&As[kk][tr4]);
            const float4 w4 = *reinterpret_cast<const float4*>(&Ws[kk][tc4]);
            const float a[4] = {a4.x, a4.y, a4.z, a4.w};
            const float w[4] = {w4.x, w4.y, w4.z, w4.w};
            #pragma unroll
            for (int i = 0; i < 4; ++i)
                #pragma unroll
                for (int j = 0; j < 4; ++j)
                    acc[i][j] = fmaf(a[i], w[j], acc[i][j]);
        }
    }

    const int h = n0 >> 6;                 // head index (BN==HD==64)
    const float scale = (z == 0) ? 0.125f : 1.0f;
    float bj[4];
    #pragma unroll
    for (int j = 0; j < 4; ++j) bj[j] = bias[n0 + tc4 + j];

    #pragma unroll
    for (int i = 0; i < 4; ++i) {
        const int r = m0 + tr4 + i;
        const int t = r >> 3, b = r & 7;
        const size_t base = ((size_t)(b * H_ + h) * T_ + t) * HD_ + tc4;
        float4 c;
        c.x = (acc[i][0] + bj[0]) * scale;
        c.y = (acc[i][1] + bj[1]) * scale;
        c.z = (acc[i][2] + bj[2]) * scale;
        c.w = (acc[i][3] + bj[3]) * scale;
        *reinterpret_cast<float4*>(&dst[base]) = c;
    }
}

// ---------------------------------------------------------------------------
// Kernel 2: flash attention, fp32.  One block = one head x 64 q-rows.
// K/V tiles of 64.  Score + PV phases are 64x64x64 register-blocked GEMMs.
// ---------------------------------------------------------------------------
__global__ __launch_bounds__(256)
void attn_kernel(const float* __restrict__ qh, const float* __restrict__ kh,
                 const float* __restrict__ vh, float* __restrict__ ao)
{
    const int qt  = blockIdx.x;   // 0..15
    const int bh  = blockIdx.y;   // 0..95
    const int tid = threadIdx.x;
    const int tr = tid >> 4, tc = tid & 15;
    const int tr4 = tr * 4, tc4 = tc * 4;

    __shared__ float Qs[64][68];  // [e][r]
    __shared__ float Ks[64][68];  // [e][c]
    __shared__ float Vs[64][68];  // [c][e]
    __shared__ float Ps[64][68];  // [c][r]

    const size_t head_base = (size_t)bh * T_ * HD_;

    // load Q tile (transposed into [e][r])
    #pragma unroll
    for (int u = 0; u < 4; ++u) {
        const int slot = tid + u * 256;      // 0..1023
        const int r  = slot >> 4;
        const int e4 = (slot & 15) * 4;
        const float4 v = *reinterpret_cast<const float4*>(
            &qh[head_base + (size_t)(qt * 64 + r) * HD_ + e4]);
        Qs[e4 + 0][r] = v.x; Qs[e4 + 1][r] = v.y;
        Qs[e4 + 2][r] = v.z; Qs[e4 + 3][r] = v.w;
    }

    float m[4], l[4] = {0.f, 0.f, 0.f, 0.f};
    float o[4][4] = {};
    #pragma unroll
    for (int i = 0; i < 4; ++i) m[i] = -1e30f;

    for (int kt = 0; kt < 16; ++kt) {
        __syncthreads();   // prev-iter readers done before overwriting Ks/Vs
        #pragma unroll
        for (int u = 0; u < 4; ++u) {
            const int slot = tid + u * 256;
            const int c  = slot >> 4;
            const int e4 = (slot & 15) * 4;
            const size_t g = head_base + (size_t)(kt * 64 + c) * HD_ + e4;
            const float4 kv = *reinterpret_cast<const float4*>(&kh[g]);
            Ks[e4 + 0][c] = kv.x; Ks[e4 + 1][c] = kv.y;
            Ks[e4 + 2][c] = kv.z; Ks[e4 + 3][c] = kv.w;
            const float4 vv = *reinterpret_cast<const float4*>(&vh[g]);
            *reinterpret_cast<float4*>(&Vs[c][e4]) = vv;
        }
        __syncthreads();

        // scores: s[i][j] = Q[row 4tr+i] . K[col 4tc+j]
        float s[4][4] = {};
        #pragma unroll
        for (int e = 0; e < 64; ++e) {
            const float4 q4 = *reinterpret_cast<const float4*>(&Qs[e][tr4]);
            const float4 k4 = *reinterpret_cast<const float4*>(&Ks[e][tc4]);
            const float a[4] = {q4.x, q4.y, q4.z, q4.w};
            const float w[4] = {k4.x, k4.y, k4.z, k4.w};
            #pragma unroll
            for (int i = 0; i < 4; ++i)
                #pragma unroll
                for (int j = 0; j < 4; ++j)
                    s[i][j] = fmaf(a[i], w[j], s[i][j]);
        }

        // online softmax (rows shared by 16 consecutive lanes -> shfl reduce)
        #pragma unroll
        for (int i = 0; i < 4; ++i) {
            float tm = fmaxf(fmaxf(s[i][0], s[i][1]), fmaxf(s[i][2], s[i][3]));
            #pragma unroll
            for (int off = 1; off < 16; off <<= 1)
                tm = fmaxf(tm, __shfl_xor(tm, off));
            const float mn = fmaxf(m[i], tm);
            const float sc = __expf(m[i] - mn);
            float rs = 0.f;
            #pragma unroll
            for (int j = 0; j < 4; ++j) {
                s[i][j] = __expf(s[i][j] - mn);
                rs += s[i][j];
            }
            #pragma unroll
            for (int off = 1; off < 16; off <<= 1)
                rs += __shfl_xor(rs, off);
            l[i] = l[i] * sc + rs;
            m[i] = mn;
            #pragma unroll
            for (int j = 0; j < 4; ++j) o[i][j] *= sc;
        }

        // write P transposed [c][r]
        #pragma unroll
        for (int j = 0; j < 4; ++j) {
            float4 w;
            w.x = s[0][j]; w.y = s[1][j]; w.z = s[2][j]; w.w = s[3][j];
            *reinterpret_cast<float4*>(&Ps[tc4 + j][tr4]) = w;
        }
        __syncthreads();

        // PV: o[i][j] += sum_c P[row][c] * V[c][e]
        #pragma unroll
        for (int c = 0; c < 64; ++c) {
            const float4 p4 = *reinterpret_cast<const float4*>(&Ps[c][tr4]);
            const float4 v4 = *reinterpret_cast<const float4*>(&Vs[c][tc4]);
            const float a[4] = {p4.x, p4.y, p4.z, p4.w};
            const float w[4] = {v4.x, v4.y, v4.z, v4.w};
            #pragma unroll
            for (int i = 0; i < 4; ++i)
                #pragma unroll
                for (int j = 0; j < 4; ++j)
                    o[i][j] = fmaf(a[i], w[j], o[i][j]);
        }
    }

    // epilogue: normalize and write attn_out in (T*B, D) row-major
    const int b = bh / H_, h = bh % H_;
    #pragma unroll
    for (int i = 0; i < 4; ++i) {
        const float inv = 1.0f / l[i];
        const int t = qt * 64 + tr4 + i;
        float4 c;
        c.x = o[i][0] * inv; c.y = o[i][1] * inv;
        c.z = o[i][2] * inv; c.w = o[i][3] * inv;
        *reinterpret_cast<float4*>(
            &ao[((size_t)t * B_ + b) * D_ + h * HD_ + tc4]) = c;
    }
}

// ---------------------------------------------------------------------------
// Kernel 3: output projection.  out = AO @ Wo^T + bo, row-major store.
// ---------------------------------------------------------------------------
__global__ __launch_bounds__(256)
void out_proj_kernel(const float* __restrict__ ao, const float* __restrict__ Wo,
                     const float* __restrict__ bo, float* __restrict__ out)
{
    const int m0 = blockIdx.y * 64;
    const int n0 = blockIdx.x * 64;
    const int tid = threadIdx.x;
    const int tr = tid >> 4, tc = tid & 15;
    const int tr4 = tr * 4, tc4 = tc * 4;

    __shared__ float As[16][68];
    __shared__ float Ws[16][68];

    float acc[4][4] = {};
    const int lr = tid >> 2;
    const int lk = (tid & 3) * 4;

    for (int kt = 0; kt < D_; kt += 16) {
        const float4 av = *reinterpret_cast<const float4*>(
            &ao[(size_t)(m0 + lr) * D_ + kt + lk]);
        const float4 wv = *reinterpret_cast<const float4*>(
            &Wo[(size_t)(n0 + lr) * D_ + kt + lk]);
        __syncthreads();
        As[lk + 0][lr] = av.x; As[lk + 1][lr] = av.y;
        As[lk + 2][lr] = av.z; As[lk + 3][lr] = av.w;
        Ws[lk + 0][lr] = wv.x; Ws[lk + 1][lr] = wv.y;
        Ws[lk + 2][lr] = wv.z; Ws[lk + 3][lr] = wv.w;
        __syncthreads();
        #pragma unroll
        for (int kk = 0; kk < 16; ++kk) {
            const float4 a4 = *reinterpret_cast<const float4*>(&As[kk][tr4]);
            const float4 w4 = *reinterpret_cast<const float4*>(&Ws[kk][tc4]);
            const float a[4] = {a4.x, a4.y, a4.z, a4.w};
            const float w[4] = {w4.x, w4.y, w4.z, w4.w};
            #pragma unroll
            for (int i = 0; i < 4; ++i)
                #pragma unroll
                for (int j = 0; j < 4; ++j)
                    acc[i][j] = fmaf(a[i], w[j], acc[i][j]);
        }
    }

    float bj[4];
    #pragma unroll
    for (int j = 0; j < 4; ++j) bj[j] = bo[n0 + tc4 + j];

    #pragma unroll
    for (int i = 0; i < 4; ++i) {
        const int r = m0 + tr4 + i;
        float4 c;
        c.x = acc[i][0] + bj[0]; c.y = acc[i][1] + bj[1];
        c.z = acc[i][2] + bj[2]; c.w = acc[i][3] + bj[3];
        *reinterpret_cast<float4*>(&out[(size_t)r * D_ + n0 + tc4]) = c;
    }
}

// ---------------------------------------------------------------------------
extern "C" void kernel_launch(void* const* d_in, const int* in_sizes, int n_in,
                              void* d_out, int out_size, void* d_ws, size_t ws_size,
                              hipStream_t stream)
{
    const float* query = (const float*)d_in[0];
    const float* keyi  = (const float*)d_in[1];
    const float* value = (const float*)d_in[2];
    const int*   lsp   = (const int*)  d_in[3];
    const float* Wq  = (const float*)d_in[4],  *bq  = (const float*)d_in[5];
    const float* Wk  = (const float*)d_in[6],  *bk  = (const float*)d_in[7];
    const float* Wv  = (const float*)d_in[8],  *bv  = (const float*)d_in[9];
    const float* Wqm = (const float*)d_in[10], *bqm = (const float*)d_in[11];
    const float* Wkm = (const float*)d_in[12], *bkm = (const float*)d_in[13];
    const float* Wvm = (const float*)d_in[14], *bvm = (const float*)d_in[15];
    const float* Wo  = (const float*)d_in[16], *bo  = (const float*)d_in[17];

    float* ws = (float*)d_ws;
    const size_t HSZ = (size_t)BH_ * T_ * HD_;   // 6291456 floats
    float* qh = ws;
    float* kh = ws + HSZ;
    float* vh = ws + 2 * HSZ;
    float* ao = ws + 3 * HSZ;

    dim3 g1(D_ / 64, M_ / 64, 3);   // (12, 128, 3)
    qkv_proj_kernel<<<g1, 256, 0, stream>>>(query, keyi, value, lsp,
                                            Wq, bq, Wk, bk, Wv, bv,
                                            Wqm, bqm, Wkm, bkm, Wvm, bvm,
                                            qh, kh, vh);

    dim3 g2(T_ / 64, BH_);          // (16, 96)
    attn_kernel<<<g2, 256, 0, stream>>>(qh, kh, vh, ao);

    dim3 g3(D_ / 64, M_ / 64);      // (12, 128)
    out_proj_kernel<<<g3, 256, 0, stream>>>(ao, Wo, bo, (float*)d_out);
}

// Round 2
// 647.228 us; speedup vs baseline: 1.8160x; 1.8160x over previous
//
#include <hip/hip_runtime.h>

#define T_  1024
#define B_  8
#define D_  768
#define H_  12
#define HD_ 64
#define BH_ 96
#define M_  8192   // T_*B_

typedef __attribute__((ext_vector_type(8))) short short8;
typedef __attribute__((ext_vector_type(4))) float f32x4;

__device__ __forceinline__ unsigned short f2bf(float f) {
    unsigned int u = __float_as_uint(f);
    u += 0x7FFF + ((u >> 16) & 1);          // round-to-nearest-even
    return (unsigned short)(u >> 16);
}

// ---------------------------------------------------------------------------
// Kernel 1: fused QKV projection (fp32 compute).  C = X @ W^T + b with modal
// row split.  Outputs bf16: q,k in head layout [bh][t][64]; v TRANSPOSED
// [bh][64][t] so attention PV B-fragments are contiguous row reads.
// ---------------------------------------------------------------------------
__global__ __launch_bounds__(256)
void qkv_proj_kernel(const float* __restrict__ query,
                     const float* __restrict__ keyi,
                     const float* __restrict__ value,
                     const int*   __restrict__ ls_ptr,
                     const float* __restrict__ Wq,  const float* __restrict__ bq,
                     const float* __restrict__ Wk,  const float* __restrict__ bk,
                     const float* __restrict__ Wv,  const float* __restrict__ bv,
                     const float* __restrict__ Wqm, const float* __restrict__ bqm,
                     const float* __restrict__ Wkm, const float* __restrict__ bkm,
                     const float* __restrict__ Wvm, const float* __restrict__ bvm,
                     unsigned short* __restrict__ qh,
                     unsigned short* __restrict__ kh,
                     unsigned short* __restrict__ vt)
{
    const int z  = blockIdx.z;          // 0=q 1=k 2=v
    const int m0 = blockIdx.y * 64;
    const int n0 = blockIdx.x * 64;
    const int tid = threadIdx.x;
    const int tr = tid >> 4, tc = tid & 15;
    const int tr4 = tr * 4, tc4 = tc * 4;

    const int  ls_row = ls_ptr[0] * B_;
    const bool modal  = (m0 >= ls_row);     // 64-aligned boundary (ls_len%8==0)

    const float* X; const float* W; const float* bias;
    if (z == 0)      { X = query; W = modal ? Wqm : Wq; bias = modal ? bqm : bq; }
    else if (z == 1) { X = keyi;  W = modal ? Wkm : Wk; bias = modal ? bkm : bk; }
    else             { X = value; W = modal ? Wvm : Wv; bias = modal ? bvm : bv; }

    __shared__ float As[16][68];
    __shared__ float Ws[16][68];

    float acc[4][4] = {};
    const int lr = tid >> 2;
    const int lk = (tid & 3) * 4;

    for (int kt = 0; kt < D_; kt += 16) {
        const float4 av = *reinterpret_cast<const float4*>(
            &X[(size_t)(m0 + lr) * D_ + kt + lk]);
        const float4 wv = *reinterpret_cast<const float4*>(
            &W[(size_t)(n0 + lr) * D_ + kt + lk]);
        __syncthreads();
        As[lk + 0][lr] = av.x; As[lk + 1][lr] = av.y;
        As[lk + 2][lr] = av.z; As[lk + 3][lr] = av.w;
        Ws[lk + 0][lr] = wv.x; Ws[lk + 1][lr] = wv.y;
        Ws[lk + 2][lr] = wv.z; Ws[lk + 3][lr] = wv.w;
        __syncthreads();
        #pragma unroll
        for (int kk = 0; kk < 16; ++kk) {
            const float4 a4 = *reinterpret_cast<const float4*>(&As[kk][tr4]);
            const float4 w4 = *reinterpret_cast<const float4*>(&Ws[kk][tc4]);
            const float a[4] = {a4.x, a4.y, a4.z, a4.w};
            const float w[4] = {w4.x, w4.y, w4.z, w4.w};
            #pragma unroll
            for (int i = 0; i < 4; ++i)
                #pragma unroll
                for (int j = 0; j < 4; ++j)
                    acc[i][j] = fmaf(a[i], w[j], acc[i][j]);
        }
    }

    const int h = n0 >> 6;
    float bj[4];
    #pragma unroll
    for (int j = 0; j < 4; ++j) bj[j] = bias[n0 + tc4 + j];

    if (z < 2) {
        const float scale = (z == 0) ? 0.125f : 1.0f;
        unsigned short* dst = (z == 0) ? qh : kh;
        #pragma unroll
        for (int i = 0; i < 4; ++i) {
            const int r = m0 + tr4 + i;
            const int t = r >> 3, b = r & 7;
            const size_t base = ((size_t)(b * H_ + h) * T_ + t) * HD_ + tc4;
            ushort4 c;
            c.x = f2bf((acc[i][0] + bj[0]) * scale);
            c.y = f2bf((acc[i][1] + bj[1]) * scale);
            c.z = f2bf((acc[i][2] + bj[2]) * scale);
            c.w = f2bf((acc[i][3] + bj[3]) * scale);
            *reinterpret_cast<ushort4*>(&dst[base]) = c;
        }
    } else {
        #pragma unroll
        for (int i = 0; i < 4; ++i) {
            const int r = m0 + tr4 + i;
            const int t = r >> 3, b = r & 7;
            const size_t hb = (size_t)(b * H_ + h) * HD_ * T_;
            #pragma unroll
            for (int j = 0; j < 4; ++j)
                vt[hb + (size_t)(tc4 + j) * T_ + t] = f2bf(acc[i][j] + bj[j]);
        }
    }
}

// ---------------------------------------------------------------------------
// Kernel 2: flash attention, bf16 MFMA (16x16x32).  Block = (head, 64 q-rows),
// 4 waves x 16 q-rows.  KV tiles of 64.  XOR-swizzled LDS (G4) for
// conflict-free ds_read_b128 fragment reads.
// ---------------------------------------------------------------------------
__global__ __launch_bounds__(256)
void attn_kernel_bf16(const unsigned short* __restrict__ qh,
                      const unsigned short* __restrict__ kh,
                      const unsigned short* __restrict__ vt,
                      float* __restrict__ ao)
{
    const int qt  = blockIdx.x;   // 0..15
    const int bh  = blockIdx.y;   // 0..95
    const int tid = threadIdx.x;
    const int w   = tid >> 6;     // wave 0..3
    const int l   = tid & 63;
    const int lr  = l & 15;
    const int lg  = l >> 4;       // 0..3

    __shared__ unsigned short Ks[64 * 64];   // [s][k]   swizzled
    __shared__ unsigned short Vt[64 * 64];   // [e][s]   swizzled
    __shared__ unsigned short Ps[64 * 64];   // [q][s]   swizzled

    const size_t qk_head = (size_t)bh * T_ * HD_;
    const size_t vt_head = (size_t)bh * HD_ * T_;

    // Q fragments in registers (rows 16w+lr, two 32-k chunks)
    short8 qf[2];
    #pragma unroll
    for (int c = 0; c < 2; ++c)
        qf[c] = *reinterpret_cast<const short8*>(
            &qh[qk_head + (size_t)(qt * 64 + 16 * w + lr) * HD_ + 8 * lg + 32 * c]);

    f32x4 o[4];
    #pragma unroll
    for (int ef = 0; ef < 4; ++ef) o[ef] = (f32x4){0.f, 0.f, 0.f, 0.f};
    float mrow[4] = {-1e30f, -1e30f, -1e30f, -1e30f};
    float lsum[4] = {0.f, 0.f, 0.f, 0.f};

    for (int kt = 0; kt < 16; ++kt) {
        __syncthreads();   // all fragment reads of previous tile done
        #pragma unroll
        for (int p = 0; p < 2; ++p) {
            const int slot = tid + p * 256;
            const int row  = slot >> 3;       // 0..63
            const int ch   = slot & 7;        // 16B chunk
            const int sw   = (ch ^ (row & 7)) * 8;
            const short8 kd = *reinterpret_cast<const short8*>(
                &kh[qk_head + (size_t)(kt * 64 + row) * HD_ + 8 * ch]);
            *reinterpret_cast<short8*>(&Ks[row * 64 + sw]) = kd;
            const short8 vd = *reinterpret_cast<const short8*>(
                &vt[vt_head + (size_t)row * T_ + kt * 64 + 8 * ch]);
            *reinterpret_cast<short8*>(&Vt[row * 64 + sw]) = vd;
        }
        __syncthreads();

        // ---- S = Q K^T : 8 MFMA ----
        f32x4 s[4];
        #pragma unroll
        for (int nf = 0; nf < 4; ++nf) s[nf] = (f32x4){0.f, 0.f, 0.f, 0.f};
        #pragma unroll
        for (int c = 0; c < 2; ++c) {
            #pragma unroll
            for (int nf = 0; nf < 4; ++nf) {
                const int row = 16 * nf + lr;
                const short8 kb = *reinterpret_cast<const short8*>(
                    &Ks[row * 64 + ((8 * lg + 32 * c) ^ ((row & 7) << 3))]);
                s[nf] = __builtin_amdgcn_mfma_f32_16x16x32_bf16(qf[c], kb, s[nf], 0, 0, 0);
            }
        }

        // ---- online softmax: lane holds rows 4lg+r, col 16nf+lr ----
        #pragma unroll
        for (int r = 0; r < 4; ++r) {
            float tm = fmaxf(fmaxf(s[0][r], s[1][r]), fmaxf(s[2][r], s[3][r]));
            tm = fmaxf(tm, __shfl_xor(tm, 1));
            tm = fmaxf(tm, __shfl_xor(tm, 2));
            tm = fmaxf(tm, __shfl_xor(tm, 4));
            tm = fmaxf(tm, __shfl_xor(tm, 8));
            const float mn = fmaxf(mrow[r], tm);
            const float sc = __expf(mrow[r] - mn);
            mrow[r] = mn;
            float pv[4], rs = 0.f;
            #pragma unroll
            for (int nf = 0; nf < 4; ++nf) { pv[nf] = __expf(s[nf][r] - mn); rs += pv[nf]; }
            rs += __shfl_xor(rs, 1);
            rs += __shfl_xor(rs, 2);
            rs += __shfl_xor(rs, 4);
            rs += __shfl_xor(rs, 8);
            lsum[r] = lsum[r] * sc + rs;
            #pragma unroll
            for (int ef = 0; ef < 4; ++ef) o[ef][r] *= sc;
            // P -> LDS (bf16, swizzled)
            const int q  = 16 * w + 4 * lg + r;
            const int qx = (q & 7) << 3;
            #pragma unroll
            for (int nf = 0; nf < 4; ++nf)
                Ps[q * 64 + ((16 * nf + lr) ^ qx)] = f2bf(pv[nf]);
        }
        __syncthreads();

        // ---- O += P V : 8 MFMA ----
        const int prow = 16 * w + lr;
        #pragma unroll
        for (int c = 0; c < 2; ++c) {
            const short8 pa = *reinterpret_cast<const short8*>(
                &Ps[prow * 64 + ((8 * lg + 32 * c) ^ ((prow & 7) << 3))]);
            #pragma unroll
            for (int ef = 0; ef < 4; ++ef) {
                const int vrow = 16 * ef + lr;
                const short8 vb = *reinterpret_cast<const short8*>(
                    &Vt[vrow * 64 + ((8 * lg + 32 * c) ^ ((vrow & 7) << 3))]);
                o[ef] = __builtin_amdgcn_mfma_f32_16x16x32_bf16(pa, vb, o[ef], 0, 0, 0);
            }
        }
    }

    // ---- epilogue: normalize, write fp32 attn-out in (T*B, D) ----
    const int b = bh / H_, h = bh % H_;
    #pragma unroll
    for (int r = 0; r < 4; ++r) {
        const int t = qt * 64 + 16 * w + 4 * lg + r;
        const float inv = 1.0f / lsum[r];
        #pragma unroll
        for (int ef = 0; ef < 4; ++ef)
            ao[((size_t)t * B_ + b) * D_ + h * HD_ + 16 * ef + lr] = o[ef][r] * inv;
    }
}

// ---------------------------------------------------------------------------
// Kernel 3: output projection (fp32).  out = AO @ Wo^T + bo.
// ---------------------------------------------------------------------------
__global__ __launch_bounds__(256)
void out_proj_kernel(const float* __restrict__ ao, const float* __restrict__ Wo,
                     const float* __restrict__ bo, float* __restrict__ out)
{
    const int m0 = blockIdx.y * 64;
    const int n0 = blockIdx.x * 64;
    const int tid = threadIdx.x;
    const int tr = tid >> 4, tc = tid & 15;
    const int tr4 = tr * 4, tc4 = tc * 4;

    __shared__ float As[16][68];
    __shared__ float Ws[16][68];

    float acc[4][4] = {};
    const int lr = tid >> 2;
    const int lk = (tid & 3) * 4;

    for (int kt = 0; kt < D_; kt += 16) {
        const float4 av = *reinterpret_cast<const float4*>(
            &ao[(size_t)(m0 + lr) * D_ + kt + lk]);
        const float4 wv = *reinterpret_cast<const float4*>(
            &Wo[(size_t)(n0 + lr) * D_ + kt + lk]);
        __syncthreads();
        As[lk + 0][lr] = av.x; As[lk + 1][lr] = av.y;
        As[lk + 2][lr] = av.z; As[lk + 3][lr] = av.w;
        Ws[lk + 0][lr] = wv.x; Ws[lk + 1][lr] = wv.y;
        Ws[lk + 2][lr] = wv.z; Ws[lk + 3][lr] = wv.w;
        __syncthreads();
        #pragma unroll
        for (int kk = 0; kk < 16; ++kk) {
            const float4 a4 = *reinterpret_cast<const float4*>(&As[kk][tr4]);
            const float4 w4 = *reinterpret_cast<const float4*>(&Ws[kk][tc4]);
            const float a[4] = {a4.x, a4.y, a4.z, a4.w};
            const float w[4] = {w4.x, w4.y, w4.z, w4.w};
            #pragma unroll
            for (int i = 0; i < 4; ++i)
                #pragma unroll
                for (int j = 0; j < 4; ++j)
                    acc[i][j] = fmaf(a[i], w[j], acc[i][j]);
        }
    }

    float bj[4];
    #pragma unroll
    for (int j = 0; j < 4; ++j) bj[j] = bo[n0 + tc4 + j];

    #pragma unroll
    for (int i = 0; i < 4; ++i) {
        const int r = m0 + tr4 + i;
        float4 c;
        c.x = acc[i][0] + bj[0]; c.y = acc[i][1] + bj[1];
        c.z = acc[i][2] + bj[2]; c.w = acc[i][3] + bj[3];
        *reinterpret_cast<float4*>(&out[(size_t)r * D_ + n0 + tc4]) = c;
    }
}

// ---------------------------------------------------------------------------
extern "C" void kernel_launch(void* const* d_in, const int* in_sizes, int n_in,
                              void* d_out, int out_size, void* d_ws, size_t ws_size,
                              hipStream_t stream)
{
    const float* query = (const float*)d_in[0];
    const float* keyi  = (const float*)d_in[1];
    const float* value = (const float*)d_in[2];
    const int*   lsp   = (const int*)  d_in[3];
    const float* Wq  = (const float*)d_in[4],  *bq  = (const float*)d_in[5];
    const float* Wk  = (const float*)d_in[6],  *bk  = (const float*)d_in[7];
    const float* Wv  = (const float*)d_in[8],  *bv  = (const float*)d_in[9];
    const float* Wqm = (const float*)d_in[10], *bqm = (const float*)d_in[11];
    const float* Wkm = (const float*)d_in[12], *bkm = (const float*)d_in[13];
    const float* Wvm = (const float*)d_in[14], *bvm = (const float*)d_in[15];
    const float* Wo  = (const float*)d_in[16], *bo  = (const float*)d_in[17];

    const size_t HSZ = (size_t)BH_ * T_ * HD_;       // 6291456 elems
    unsigned short* qh = (unsigned short*)d_ws;
    unsigned short* kh = qh + HSZ;
    unsigned short* vt = kh + HSZ;
    float*          ao = (float*)(vt + HSZ);

    dim3 g1(D_ / 64, M_ / 64, 3);
    qkv_proj_kernel<<<g1, 256, 0, stream>>>(query, keyi, value, lsp,
                                            Wq, bq, Wk, bk, Wv, bv,
                                            Wqm, bqm, Wkm, bkm, Wvm, bvm,
                                            qh, kh, vt);

    dim3 g2(T_ / 64, BH_);
    attn_kernel_bf16<<<g2, 256, 0, stream>>>(qh, kh, vt, ao);

    dim3 g3(D_ / 64, M_ / 64);
    out_proj_kernel<<<g3, 256, 0, stream>>>(ao, Wo, bo, (float*)d_out);
}

// Round 3
// 255.498 us; speedup vs baseline: 4.6003x; 2.5332x over previous
//
#include <hip/hip_runtime.h>

#define T_  1024
#define B_  8
#define D_  768
#define H_  12
#define HD_ 64
#define BH_ 96
#define M_  8192           // T_*B_
#define XSZ 6291456ull     // T_*B_*D_
#define WSZ 589824ull      // D_*D_

typedef __attribute__((ext_vector_type(8))) short short8;
typedef __attribute__((ext_vector_type(4))) float f32x4;

__device__ __forceinline__ unsigned short f2bf(float f) {
    unsigned int u = __float_as_uint(f);
    u += 0x7FFF + ((u >> 16) & 1);          // round-to-nearest-even
    return (unsigned short)(u >> 16);
}

__device__ __forceinline__ void g2lds16(const unsigned short* g, unsigned short* l) {
    __builtin_amdgcn_global_load_lds(
        (const __attribute__((address_space(1))) unsigned int*)(g),
        (__attribute__((address_space(3))) unsigned int*)(l),
        16, 0, 0);
}

// ---------------------------------------------------------------------------
// Kernel 0: fp32 -> bf16 conversion of X (q,k,v) and the 7 weight matrices.
// dst layout: [xq xk xv][Wq Wk Wv Wqm Wkm Wvm Wo]
// ---------------------------------------------------------------------------
__global__ __launch_bounds__(256)
void convert_kernel(const float* __restrict__ q, const float* __restrict__ k,
                    const float* __restrict__ v,
                    const float* __restrict__ wq, const float* __restrict__ wk,
                    const float* __restrict__ wv, const float* __restrict__ wqm,
                    const float* __restrict__ wkm, const float* __restrict__ wvm,
                    const float* __restrict__ wo,
                    unsigned short* __restrict__ dst)
{
    const int seg = blockIdx.y;
    const float* s; size_t off, n;
    switch (seg) {
        case 0: s = q;   off = 0;               n = XSZ; break;
        case 1: s = k;   off = XSZ;             n = XSZ; break;
        case 2: s = v;   off = 2*XSZ;           n = XSZ; break;
        case 3: s = wq;  off = 3*XSZ;           n = WSZ; break;
        case 4: s = wk;  off = 3*XSZ +   WSZ;   n = WSZ; break;
        case 5: s = wv;  off = 3*XSZ + 2*WSZ;   n = WSZ; break;
        case 6: s = wqm; off = 3*XSZ + 3*WSZ;   n = WSZ; break;
        case 7: s = wkm; off = 3*XSZ + 4*WSZ;   n = WSZ; break;
        case 8: s = wvm; off = 3*XSZ + 5*WSZ;   n = WSZ; break;
        default:s = wo;  off = 3*XSZ + 6*WSZ;   n = WSZ; break;
    }
    unsigned short* d = dst + off;
    const size_t stride = (size_t)gridDim.x * blockDim.x;
    for (size_t i = (size_t)blockIdx.x * blockDim.x + threadIdx.x; i < n / 4; i += stride) {
        const float4 f = reinterpret_cast<const float4*>(s)[i];
        ushort4 o;
        o.x = f2bf(f.x); o.y = f2bf(f.y); o.z = f2bf(f.z); o.w = f2bf(f.w);
        reinterpret_cast<ushort4*>(d)[i] = o;
    }
}

// ---------------------------------------------------------------------------
// Shared GEMM core: C(128x128) = A(128xK) @ B(128xK)^T, bf16 MFMA 16x16x32,
// K=768, BK=32, 4 waves (2x2 quadrants), double-buffered LDS via
// global_load_lds(16).  LDS layout per buf: A then B, each chunk-major
// [4][128][8] so fragment ds_read_b128 is conflict-free with linear staging.
// ---------------------------------------------------------------------------
__device__ __forceinline__ void stage_tile(const unsigned short* __restrict__ A,
                                           const unsigned short* __restrict__ B,
                                           int m0, int n0, int ks,
                                           unsigned short* lds, int buf, int tid)
{
    const int w = tid >> 6;
    #pragma unroll
    for (int p = 0; p < 2; ++p) {
        const int idx = p * 256 + tid;
        const int row = idx & 127, ch = idx >> 7;
        unsigned short* la = &lds[buf * 8192 +        (p * 256 + w * 64) * 8];
        unsigned short* lb = &lds[buf * 8192 + 4096 + (p * 256 + w * 64) * 8];
        g2lds16(&A[(size_t)(m0 + row) * D_ + ks * 32 + ch * 8], la);
        g2lds16(&B[(size_t)(n0 + row) * D_ + ks * 32 + ch * 8], lb);
    }
}

__device__ __forceinline__ void mfma_step(const unsigned short* lds, int buf,
                                          int wr, int wc, int lr, int lg,
                                          f32x4 acc[4][4])
{
    short8 a[4], b[4];
    #pragma unroll
    for (int m = 0; m < 4; ++m)
        a[m] = *reinterpret_cast<const short8*>(
            &lds[buf * 8192 + lg * 1024 + (wr * 64 + 16 * m + lr) * 8]);
    #pragma unroll
    for (int n = 0; n < 4; ++n)
        b[n] = *reinterpret_cast<const short8*>(
            &lds[buf * 8192 + 4096 + lg * 1024 + (wc * 64 + 16 * n + lr) * 8]);
    #pragma unroll
    for (int m = 0; m < 4; ++m)
        #pragma unroll
        for (int n = 0; n < 4; ++n)
            acc[m][n] = __builtin_amdgcn_mfma_f32_16x16x32_bf16(a[m], b[n], acc[m][n], 0, 0, 0);
}

#define GEMM_CORE(Aptr, Bptr)                                                  \
    f32x4 acc[4][4];                                                           \
    _Pragma("unroll") for (int m = 0; m < 4; ++m)                              \
        _Pragma("unroll") for (int n = 0; n < 4; ++n)                          \
            acc[m][n] = (f32x4){0.f, 0.f, 0.f, 0.f};                           \
    stage_tile(Aptr, Bptr, m0, n0, 0, lds, 0, tid);                            \
    __syncthreads();                                                           \
    int cur = 0;                                                               \
    for (int ks = 0; ks < 24; ++ks) {                                          \
        if (ks < 23) stage_tile(Aptr, Bptr, m0, n0, ks + 1, lds, cur ^ 1, tid);\
        mfma_step(lds, cur, wr, wc, lr, lg, acc);                              \
        __syncthreads();                                                       \
        cur ^= 1;                                                              \
    }

// ---------------------------------------------------------------------------
// Kernel 1: QKV projection GEMM (bf16 MFMA).  z = 0/1/2 -> q/k/v, modal row
// split on weight select.  q,k -> head layout [bh][t][64] (q scaled);
// v -> transposed [bh][64][t].
// ---------------------------------------------------------------------------
__global__ __launch_bounds__(256)
void qkv_gemm(const unsigned short* __restrict__ xb,
              const unsigned short* __restrict__ wb,
              const int* __restrict__ ls_ptr,
              const float* __restrict__ bq,  const float* __restrict__ bk,
              const float* __restrict__ bv,  const float* __restrict__ bqm,
              const float* __restrict__ bkm, const float* __restrict__ bvm,
              unsigned short* __restrict__ qh, unsigned short* __restrict__ kh,
              unsigned short* __restrict__ vt)
{
    __shared__ unsigned short lds[16384];
    const int z  = blockIdx.z;
    const int m0 = blockIdx.y * 128, n0 = blockIdx.x * 128;
    const int tid = threadIdx.x;
    const int w = tid >> 6, l = tid & 63, lr = l & 15, lg = l >> 4;
    const int wr = w >> 1, wc = w & 1;

    const bool modal = (m0 >= ls_ptr[0] * B_);
    const unsigned short* A = xb + (size_t)z * XSZ;
    const unsigned short* W = wb + (size_t)(z + (modal ? 3 : 0)) * WSZ;
    const float* bias = modal ? (z == 0 ? bqm : z == 1 ? bkm : bvm)
                              : (z == 0 ? bq  : z == 1 ? bk  : bv);

    GEMM_CORE(A, W)

    float bn[4];
    #pragma unroll
    for (int n = 0; n < 4; ++n) bn[n] = bias[n0 + wc * 64 + 16 * n + lr];

    if (z < 2) {
        unsigned short* dst = (z == 0) ? qh : kh;
        const float scale = (z == 0) ? 0.125f : 1.0f;
        #pragma unroll
        for (int m = 0; m < 4; ++m) {
            const int grb = m0 + wr * 64 + 16 * m + 4 * lg;
            #pragma unroll
            for (int n = 0; n < 4; ++n) {
                const int gc = n0 + wc * 64 + 16 * n + lr;
                const int h = gc >> 6, e = gc & 63;
                #pragma unroll
                for (int j = 0; j < 4; ++j) {
                    const int gr = grb + j, t = gr >> 3, b = gr & 7;
                    dst[((size_t)(b * H_ + h) * T_ + t) * HD_ + e] =
                        f2bf((acc[m][n][j] + bn[n]) * scale);
                }
            }
        }
    } else {
        #pragma unroll
        for (int m = 0; m < 4; ++m) {
            const int grb = m0 + wr * 64 + 16 * m + 4 * lg;
            #pragma unroll
            for (int n = 0; n < 4; ++n) {
                const int gc = n0 + wc * 64 + 16 * n + lr;
                const int h = gc >> 6, e = gc & 63;
                #pragma unroll
                for (int j = 0; j < 4; ++j) {
                    const int gr = grb + j, t = gr >> 3, b = gr & 7;
                    vt[((size_t)(b * H_ + h) * HD_ + e) * T_ + t] =
                        f2bf(acc[m][n][j] + bn[n]);
                }
            }
        }
    }
}

// ---------------------------------------------------------------------------
// Kernel 3: output projection GEMM (bf16 MFMA), fp32 output + bias.
// ---------------------------------------------------------------------------
__global__ __launch_bounds__(256)
void out_gemm(const unsigned short* __restrict__ aob,
              const unsigned short* __restrict__ wo,
              const float* __restrict__ bo, float* __restrict__ out)
{
    __shared__ unsigned short lds[16384];
    const int m0 = blockIdx.y * 128, n0 = blockIdx.x * 128;
    const int tid = threadIdx.x;
    const int w = tid >> 6, l = tid & 63, lr = l & 15, lg = l >> 4;
    const int wr = w >> 1, wc = w & 1;

    GEMM_CORE(aob, wo)

    float bn[4];
    #pragma unroll
    for (int n = 0; n < 4; ++n) bn[n] = bo[n0 + wc * 64 + 16 * n + lr];

    #pragma unroll
    for (int m = 0; m < 4; ++m) {
        const int grb = m0 + wr * 64 + 16 * m + 4 * lg;
        #pragma unroll
        for (int n = 0; n < 4; ++n) {
            const int gc = n0 + wc * 64 + 16 * n + lr;
            #pragma unroll
            for (int j = 0; j < 4; ++j) {
                const int gr = grb + j;
                out[(size_t)gr * D_ + gc] = acc[m][n][j] + bn[n];
            }
        }
    }
}

// ---------------------------------------------------------------------------
// Kernel 2: flash attention, bf16 MFMA (unchanged from R1 except bf16 output).
// ---------------------------------------------------------------------------
__global__ __launch_bounds__(256)
void attn_kernel_bf16(const unsigned short* __restrict__ qh,
                      const unsigned short* __restrict__ kh,
                      const unsigned short* __restrict__ vt,
                      unsigned short* __restrict__ aob)
{
    const int qt  = blockIdx.x;
    const int bh  = blockIdx.y;
    const int tid = threadIdx.x;
    const int w   = tid >> 6;
    const int l   = tid & 63;
    const int lr  = l & 15;
    const int lg  = l >> 4;

    __shared__ unsigned short Ks[64 * 64];
    __shared__ unsigned short Vt[64 * 64];
    __shared__ unsigned short Ps[64 * 64];

    const size_t qk_head = (size_t)bh * T_ * HD_;
    const size_t vt_head = (size_t)bh * HD_ * T_;

    short8 qf[2];
    #pragma unroll
    for (int c = 0; c < 2; ++c)
        qf[c] = *reinterpret_cast<const short8*>(
            &qh[qk_head + (size_t)(qt * 64 + 16 * w + lr) * HD_ + 8 * lg + 32 * c]);

    f32x4 o[4];
    #pragma unroll
    for (int ef = 0; ef < 4; ++ef) o[ef] = (f32x4){0.f, 0.f, 0.f, 0.f};
    float mrow[4] = {-1e30f, -1e30f, -1e30f, -1e30f};
    float lsum[4] = {0.f, 0.f, 0.f, 0.f};

    for (int kt = 0; kt < 16; ++kt) {
        __syncthreads();
        #pragma unroll
        for (int p = 0; p < 2; ++p) {
            const int slot = tid + p * 256;
            const int row  = slot >> 3;
            const int ch   = slot & 7;
            const int sw   = (ch ^ (row & 7)) * 8;
            const short8 kd = *reinterpret_cast<const short8*>(
                &kh[qk_head + (size_t)(kt * 64 + row) * HD_ + 8 * ch]);
            *reinterpret_cast<short8*>(&Ks[row * 64 + sw]) = kd;
            const short8 vd = *reinterpret_cast<const short8*>(
                &vt[vt_head + (size_t)row * T_ + kt * 64 + 8 * ch]);
            *reinterpret_cast<short8*>(&Vt[row * 64 + sw]) = vd;
        }
        __syncthreads();

        f32x4 s[4];
        #pragma unroll
        for (int nf = 0; nf < 4; ++nf) s[nf] = (f32x4){0.f, 0.f, 0.f, 0.f};
        #pragma unroll
        for (int c = 0; c < 2; ++c) {
            #pragma unroll
            for (int nf = 0; nf < 4; ++nf) {
                const int row = 16 * nf + lr;
                const short8 kb = *reinterpret_cast<const short8*>(
                    &Ks[row * 64 + ((8 * lg + 32 * c) ^ ((row & 7) << 3))]);
                s[nf] = __builtin_amdgcn_mfma_f32_16x16x32_bf16(qf[c], kb, s[nf], 0, 0, 0);
            }
        }

        #pragma unroll
        for (int r = 0; r < 4; ++r) {
            float tm = fmaxf(fmaxf(s[0][r], s[1][r]), fmaxf(s[2][r], s[3][r]));
            tm = fmaxf(tm, __shfl_xor(tm, 1));
            tm = fmaxf(tm, __shfl_xor(tm, 2));
            tm = fmaxf(tm, __shfl_xor(tm, 4));
            tm = fmaxf(tm, __shfl_xor(tm, 8));
            const float mn = fmaxf(mrow[r], tm);
            const float sc = __expf(mrow[r] - mn);
            mrow[r] = mn;
            float pv[4], rs = 0.f;
            #pragma unroll
            for (int nf = 0; nf < 4; ++nf) { pv[nf] = __expf(s[nf][r] - mn); rs += pv[nf]; }
            rs += __shfl_xor(rs, 1);
            rs += __shfl_xor(rs, 2);
            rs += __shfl_xor(rs, 4);
            rs += __shfl_xor(rs, 8);
            lsum[r] = lsum[r] * sc + rs;
            #pragma unroll
            for (int ef = 0; ef < 4; ++ef) o[ef][r] *= sc;
            const int q  = 16 * w + 4 * lg + r;
            const int qx = (q & 7) << 3;
            #pragma unroll
            for (int nf = 0; nf < 4; ++nf)
                Ps[q * 64 + ((16 * nf + lr) ^ qx)] = f2bf(pv[nf]);
        }
        __syncthreads();

        const int prow = 16 * w + lr;
        #pragma unroll
        for (int c = 0; c < 2; ++c) {
            const short8 pa = *reinterpret_cast<const short8*>(
                &Ps[prow * 64 + ((8 * lg + 32 * c) ^ ((prow & 7) << 3))]);
            #pragma unroll
            for (int ef = 0; ef < 4; ++ef) {
                const int vrow = 16 * ef + lr;
                const short8 vb = *reinterpret_cast<const short8*>(
                    &Vt[vrow * 64 + ((8 * lg + 32 * c) ^ ((vrow & 7) << 3))]);
                o[ef] = __builtin_amdgcn_mfma_f32_16x16x32_bf16(pa, vb, o[ef], 0, 0, 0);
            }
        }
    }

    const int b = bh / H_, h = bh % H_;
    #pragma unroll
    for (int r = 0; r < 4; ++r) {
        const int t = qt * 64 + 16 * w + 4 * lg + r;
        const float inv = 1.0f / lsum[r];
        #pragma unroll
        for (int ef = 0; ef < 4; ++ef)
            aob[((size_t)t * B_ + b) * D_ + h * HD_ + 16 * ef + lr] =
                f2bf(o[ef][r] * inv);
    }
}

// ---------------------------------------------------------------------------
extern "C" void kernel_launch(void* const* d_in, const int* in_sizes, int n_in,
                              void* d_out, int out_size, void* d_ws, size_t ws_size,
                              hipStream_t stream)
{
    const float* query = (const float*)d_in[0];
    const float* keyi  = (const float*)d_in[1];
    const float* value = (const float*)d_in[2];
    const int*   lsp   = (const int*)  d_in[3];
    const float* Wq  = (const float*)d_in[4],  *bq  = (const float*)d_in[5];
    const float* Wk  = (const float*)d_in[6],  *bk  = (const float*)d_in[7];
    const float* Wv  = (const float*)d_in[8],  *bv  = (const float*)d_in[9];
    const float* Wqm = (const float*)d_in[10], *bqm = (const float*)d_in[11];
    const float* Wkm = (const float*)d_in[12], *bkm = (const float*)d_in[13];
    const float* Wvm = (const float*)d_in[14], *bvm = (const float*)d_in[15];
    const float* Wo  = (const float*)d_in[16], *bo  = (const float*)d_in[17];

    unsigned short* ws = (unsigned short*)d_ws;
    unsigned short* xb  = ws;                       // 3*XSZ
    unsigned short* wb  = xb + 3 * XSZ;             // 7*WSZ
    unsigned short* qh  = wb + 7 * WSZ;             // XSZ
    unsigned short* kh  = qh + XSZ;                 // XSZ
    unsigned short* vt  = kh + XSZ;                 // XSZ
    unsigned short* aob = vt + XSZ;                 // XSZ

    dim3 gc_(512, 10);
    convert_kernel<<<gc_, 256, 0, stream>>>(query, keyi, value,
                                            Wq, Wk, Wv, Wqm, Wkm, Wvm, Wo, xb);

    dim3 g1(D_ / 128, M_ / 128, 3);   // (6, 64, 3)
    qkv_gemm<<<g1, 256, 0, stream>>>(xb, wb, lsp, bq, bk, bv, bqm, bkm, bvm,
                                     qh, kh, vt);

    dim3 g2(T_ / 64, BH_);            // (16, 96)
    attn_kernel_bf16<<<g2, 256, 0, stream>>>(qh, kh, vt, aob);

    dim3 g3(D_ / 128, M_ / 128);      // (6, 64)
    out_gemm<<<g3, 256, 0, stream>>>(aob, wb + 6 * WSZ, bo, (float*)d_out);
}

// Round 4
// 241.239 us; speedup vs baseline: 4.8722x; 1.0591x over previous
//
#include <hip/hip_runtime.h>

#define T_  1024
#define B_  8
#define D_  768
#define H_  12
#define HD_ 64
#define BH_ 96
#define M_  8192           // T_*B_
#define XSZ 6291456ull     // T_*B_*D_
#define WSZ 589824ull      // D_*D_

typedef __attribute__((ext_vector_type(8))) short short8;
typedef __attribute__((ext_vector_type(4))) float f32x4;

__device__ __forceinline__ unsigned short f2bf(float f) {
    unsigned int u = __float_as_uint(f);
    u += 0x7FFF + ((u >> 16) & 1);          // round-to-nearest-even
    return (unsigned short)(u >> 16);
}

__device__ __forceinline__ void g2lds16(const unsigned short* g, unsigned short* l) {
    __builtin_amdgcn_global_load_lds(
        (const __attribute__((address_space(1))) unsigned int*)(g),
        (__attribute__((address_space(3))) unsigned int*)(l),
        16, 0, 0);
}

// ---------------------------------------------------------------------------
// Kernel 0: fp32 -> bf16 conversion of X (q,k,v) and the 7 weight matrices.
// ---------------------------------------------------------------------------
__global__ __launch_bounds__(256)
void convert_kernel(const float* __restrict__ q, const float* __restrict__ k,
                    const float* __restrict__ v,
                    const float* __restrict__ wq, const float* __restrict__ wk,
                    const float* __restrict__ wv, const float* __restrict__ wqm,
                    const float* __restrict__ wkm, const float* __restrict__ wvm,
                    const float* __restrict__ wo,
                    unsigned short* __restrict__ dst)
{
    const int seg = blockIdx.y;
    const float* s; size_t off, n;
    switch (seg) {
        case 0: s = q;   off = 0;               n = XSZ; break;
        case 1: s = k;   off = XSZ;             n = XSZ; break;
        case 2: s = v;   off = 2*XSZ;           n = XSZ; break;
        case 3: s = wq;  off = 3*XSZ;           n = WSZ; break;
        case 4: s = wk;  off = 3*XSZ +   WSZ;   n = WSZ; break;
        case 5: s = wv;  off = 3*XSZ + 2*WSZ;   n = WSZ; break;
        case 6: s = wqm; off = 3*XSZ + 3*WSZ;   n = WSZ; break;
        case 7: s = wkm; off = 3*XSZ + 4*WSZ;   n = WSZ; break;
        case 8: s = wvm; off = 3*XSZ + 5*WSZ;   n = WSZ; break;
        default:s = wo;  off = 3*XSZ + 6*WSZ;   n = WSZ; break;
    }
    unsigned short* d = dst + off;
    const size_t stride = (size_t)gridDim.x * blockDim.x;
    for (size_t i = (size_t)blockIdx.x * blockDim.x + threadIdx.x; i < n / 4; i += stride) {
        const float4 f = reinterpret_cast<const float4*>(s)[i];
        ushort4 o;
        o.x = f2bf(f.x); o.y = f2bf(f.y); o.z = f2bf(f.z); o.w = f2bf(f.w);
        reinterpret_cast<ushort4*>(d)[i] = o;
    }
}

// ---------------------------------------------------------------------------
// Shared GEMM core: C(128x128) = A(128xK) @ B(128xK)^T, bf16 MFMA 16x16x32,
// K=768, BK=32, 4 waves (2x2 quadrants).  3-buffer LDS, 2-deep prefetch via
// global_load_lds(16) with COUNTED vmcnt (T3+T4): never drain to 0 in-loop.
// LDS per buf: A then B, each chunk-major [4][128][8] (conflict-free b128).
// ---------------------------------------------------------------------------
__device__ __forceinline__ void stage_tile(const unsigned short* __restrict__ A,
                                           const unsigned short* __restrict__ B,
                                           int m0, int n0, int ks,
                                           unsigned short* lds, int buf, int tid)
{
    const int w = tid >> 6;
    #pragma unroll
    for (int p = 0; p < 2; ++p) {
        const int idx = p * 256 + tid;
        const int row = idx & 127, ch = idx >> 7;
        unsigned short* la = &lds[buf * 8192 +        (p * 256 + w * 64) * 8];
        unsigned short* lb = &lds[buf * 8192 + 4096 + (p * 256 + w * 64) * 8];
        g2lds16(&A[(size_t)(m0 + row) * D_ + ks * 32 + ch * 8], la);
        g2lds16(&B[(size_t)(n0 + row) * D_ + ks * 32 + ch * 8], lb);
    }
}

__device__ __forceinline__ void mfma_step(const unsigned short* lds, int buf,
                                          int wr, int wc, int lr, int lg,
                                          f32x4 acc[4][4])
{
    short8 a[4], b[4];
    #pragma unroll
    for (int m = 0; m < 4; ++m)
        a[m] = *reinterpret_cast<const short8*>(
            &lds[buf * 8192 + lg * 1024 + (wr * 64 + 16 * m + lr) * 8]);
    #pragma unroll
    for (int n = 0; n < 4; ++n)
        b[n] = *reinterpret_cast<const short8*>(
            &lds[buf * 8192 + 4096 + lg * 1024 + (wc * 64 + 16 * n + lr) * 8]);
    #pragma unroll
    for (int m = 0; m < 4; ++m)
        #pragma unroll
        for (int n = 0; n < 4; ++n)
            acc[m][n] = __builtin_amdgcn_mfma_f32_16x16x32_bf16(a[m], b[n], acc[m][n], 0, 0, 0);
}

// 24 K-steps (K=768, BK=32).  stage(ks) waited at iter ks with vmcnt(4)
// (stage(ks+1)'s 4 loads/thread stay in flight).  lgkmcnt(0) before the
// barrier retires all ds_reads -> 3-buffer overwrite is race-free.
#define GEMM_CORE(Aptr, Bptr)                                                  \
    f32x4 acc[4][4];                                                           \
    _Pragma("unroll") for (int m = 0; m < 4; ++m)                              \
        _Pragma("unroll") for (int n = 0; n < 4; ++n)                          \
            acc[m][n] = (f32x4){0.f, 0.f, 0.f, 0.f};                           \
    stage_tile(Aptr, Bptr, m0, n0, 0, lds, 0, tid);                            \
    stage_tile(Aptr, Bptr, m0, n0, 1, lds, 1, tid);                            \
    for (int ks = 0; ks < 24; ++ks) {                                          \
        if (ks < 22) { asm volatile("s_waitcnt vmcnt(4) lgkmcnt(0)" ::: "memory"); } \
        else         { asm volatile("s_waitcnt vmcnt(0) lgkmcnt(0)" ::: "memory"); } \
        __builtin_amdgcn_sched_barrier(0);                                     \
        __builtin_amdgcn_s_barrier();                                          \
        __builtin_amdgcn_sched_barrier(0);                                     \
        if (ks < 22) stage_tile(Aptr, Bptr, m0, n0, ks + 2, lds, (ks + 2) % 3, tid); \
        mfma_step(lds, ks % 3, wr, wc, lr, lg, acc);                           \
    }

// ---------------------------------------------------------------------------
// Kernel 1: QKV projection GEMM (bf16 MFMA).  z = 0/1/2 -> q/k/v, modal row
// split on weight select.  q,k -> head layout [bh][t][64] (q scaled);
// v -> transposed [bh][64][t].
// ---------------------------------------------------------------------------
__global__ __launch_bounds__(256)
void qkv_gemm(const unsigned short* __restrict__ xb,
              const unsigned short* __restrict__ wb,
              const int* __restrict__ ls_ptr,
              const float* __restrict__ bq,  const float* __restrict__ bk,
              const float* __restrict__ bv,  const float* __restrict__ bqm,
              const float* __restrict__ bkm, const float* __restrict__ bvm,
              unsigned short* __restrict__ qh, unsigned short* __restrict__ kh,
              unsigned short* __restrict__ vt)
{
    __shared__ unsigned short lds[24576];   // 3 x 16 KB buffers
    const int z  = blockIdx.z;
    const int m0 = blockIdx.y * 128, n0 = blockIdx.x * 128;
    const int tid = threadIdx.x;
    const int w = tid >> 6, l = tid & 63, lr = l & 15, lg = l >> 4;
    const int wr = w >> 1, wc = w & 1;

    const bool modal = (m0 >= ls_ptr[0] * B_);
    const unsigned short* A = xb + (size_t)z * XSZ;
    const unsigned short* W = wb + (size_t)(z + (modal ? 3 : 0)) * WSZ;
    const float* bias = modal ? (z == 0 ? bqm : z == 1 ? bkm : bvm)
                              : (z == 0 ? bq  : z == 1 ? bk  : bv);

    GEMM_CORE(A, W)

    float bn[4];
    #pragma unroll
    for (int n = 0; n < 4; ++n) bn[n] = bias[n0 + wc * 64 + 16 * n + lr];

    if (z < 2) {
        unsigned short* dst = (z == 0) ? qh : kh;
        const float scale = (z == 0) ? 0.125f : 1.0f;
        #pragma unroll
        for (int m = 0; m < 4; ++m) {
            const int grb = m0 + wr * 64 + 16 * m + 4 * lg;
            #pragma unroll
            for (int n = 0; n < 4; ++n) {
                const int gc = n0 + wc * 64 + 16 * n + lr;
                const int h = gc >> 6, e = gc & 63;
                #pragma unroll
                for (int j = 0; j < 4; ++j) {
                    const int gr = grb + j, t = gr >> 3, b = gr & 7;
                    dst[((size_t)(b * H_ + h) * T_ + t) * HD_ + e] =
                        f2bf((acc[m][n][j] + bn[n]) * scale);
                }
            }
        }
    } else {
        #pragma unroll
        for (int m = 0; m < 4; ++m) {
            const int grb = m0 + wr * 64 + 16 * m + 4 * lg;
            #pragma unroll
            for (int n = 0; n < 4; ++n) {
                const int gc = n0 + wc * 64 + 16 * n + lr;
                const int h = gc >> 6, e = gc & 63;
                #pragma unroll
                for (int j = 0; j < 4; ++j) {
                    const int gr = grb + j, t = gr >> 3, b = gr & 7;
                    vt[((size_t)(b * H_ + h) * HD_ + e) * T_ + t] =
                        f2bf(acc[m][n][j] + bn[n]);
                }
            }
        }
    }
}

// ---------------------------------------------------------------------------
// Kernel 3: output projection GEMM (bf16 MFMA), fp32 output + bias.
// ---------------------------------------------------------------------------
__global__ __launch_bounds__(256)
void out_gemm(const unsigned short* __restrict__ aob,
              const unsigned short* __restrict__ wo,
              const float* __restrict__ bo, float* __restrict__ out)
{
    __shared__ unsigned short lds[24576];
    const int m0 = blockIdx.y * 128, n0 = blockIdx.x * 128;
    const int tid = threadIdx.x;
    const int w = tid >> 6, l = tid & 63, lr = l & 15, lg = l >> 4;
    const int wr = w >> 1, wc = w & 1;

    GEMM_CORE(aob, wo)

    float bn[4];
    #pragma unroll
    for (int n = 0; n < 4; ++n) bn[n] = bo[n0 + wc * 64 + 16 * n + lr];

    #pragma unroll
    for (int m = 0; m < 4; ++m) {
        const int grb = m0 + wr * 64 + 16 * m + 4 * lg;
        #pragma unroll
        for (int n = 0; n < 4; ++n) {
            const int gc = n0 + wc * 64 + 16 * n + lr;
            #pragma unroll
            for (int j = 0; j < 4; ++j) {
                const int gr = grb + j;
                out[(size_t)gr * D_ + gc] = acc[m][n][j] + bn[n];
            }
        }
    }
}

// ---------------------------------------------------------------------------
// Kernel 2: flash attention, bf16 MFMA (unchanged from R2).
// ---------------------------------------------------------------------------
__global__ __launch_bounds__(256)
void attn_kernel_bf16(const unsigned short* __restrict__ qh,
                      const unsigned short* __restrict__ kh,
                      const unsigned short* __restrict__ vt,
                      unsigned short* __restrict__ aob)
{
    const int qt  = blockIdx.x;
    const int bh  = blockIdx.y;
    const int tid = threadIdx.x;
    const int w   = tid >> 6;
    const int l   = tid & 63;
    const int lr  = l & 15;
    const int lg  = l >> 4;

    __shared__ unsigned short Ks[64 * 64];
    __shared__ unsigned short Vt[64 * 64];
    __shared__ unsigned short Ps[64 * 64];

    const size_t qk_head = (size_t)bh * T_ * HD_;
    const size_t vt_head = (size_t)bh * HD_ * T_;

    short8 qf[2];
    #pragma unroll
    for (int c = 0; c < 2; ++c)
        qf[c] = *reinterpret_cast<const short8*>(
            &qh[qk_head + (size_t)(qt * 64 + 16 * w + lr) * HD_ + 8 * lg + 32 * c]);

    f32x4 o[4];
    #pragma unroll
    for (int ef = 0; ef < 4; ++ef) o[ef] = (f32x4){0.f, 0.f, 0.f, 0.f};
    float mrow[4] = {-1e30f, -1e30f, -1e30f, -1e30f};
    float lsum[4] = {0.f, 0.f, 0.f, 0.f};

    for (int kt = 0; kt < 16; ++kt) {
        __syncthreads();
        #pragma unroll
        for (int p = 0; p < 2; ++p) {
            const int slot = tid + p * 256;
            const int row  = slot >> 3;
            const int ch   = slot & 7;
            const int sw   = (ch ^ (row & 7)) * 8;
            const short8 kd = *reinterpret_cast<const short8*>(
                &kh[qk_head + (size_t)(kt * 64 + row) * HD_ + 8 * ch]);
            *reinterpret_cast<short8*>(&Ks[row * 64 + sw]) = kd;
            const short8 vd = *reinterpret_cast<const short8*>(
                &vt[vt_head + (size_t)row * T_ + kt * 64 + 8 * ch]);
            *reinterpret_cast<short8*>(&Vt[row * 64 + sw]) = vd;
        }
        __syncthreads();

        f32x4 s[4];
        #pragma unroll
        for (int nf = 0; nf < 4; ++nf) s[nf] = (f32x4){0.f, 0.f, 0.f, 0.f};
        #pragma unroll
        for (int c = 0; c < 2; ++c) {
            #pragma unroll
            for (int nf = 0; nf < 4; ++nf) {
                const int row = 16 * nf + lr;
                const short8 kb = *reinterpret_cast<const short8*>(
                    &Ks[row * 64 + ((8 * lg + 32 * c) ^ ((row & 7) << 3))]);
                s[nf] = __builtin_amdgcn_mfma_f32_16x16x32_bf16(qf[c], kb, s[nf], 0, 0, 0);
            }
        }

        #pragma unroll
        for (int r = 0; r < 4; ++r) {
            float tm = fmaxf(fmaxf(s[0][r], s[1][r]), fmaxf(s[2][r], s[3][r]));
            tm = fmaxf(tm, __shfl_xor(tm, 1));
            tm = fmaxf(tm, __shfl_xor(tm, 2));
            tm = fmaxf(tm, __shfl_xor(tm, 4));
            tm = fmaxf(tm, __shfl_xor(tm, 8));
            const float mn = fmaxf(mrow[r], tm);
            const float sc = __expf(mrow[r] - mn);
            mrow[r] = mn;
            float pv[4], rs = 0.f;
            #pragma unroll
            for (int nf = 0; nf < 4; ++nf) { pv[nf] = __expf(s[nf][r] - mn); rs += pv[nf]; }
            rs += __shfl_xor(rs, 1);
            rs += __shfl_xor(rs, 2);
            rs += __shfl_xor(rs, 4);
            rs += __shfl_xor(rs, 8);
            lsum[r] = lsum[r] * sc + rs;
            #pragma unroll
            for (int ef = 0; ef < 4; ++ef) o[ef][r] *= sc;
            const int q  = 16 * w + 4 * lg + r;
            const int qx = (q & 7) << 3;
            #pragma unroll
            for (int nf = 0; nf < 4; ++nf)
                Ps[q * 64 + ((16 * nf + lr) ^ qx)] = f2bf(pv[nf]);
        }
        __syncthreads();

        const int prow = 16 * w + lr;
        #pragma unroll
        for (int c = 0; c < 2; ++c) {
            const short8 pa = *reinterpret_cast<const short8*>(
                &Ps[prow * 64 + ((8 * lg + 32 * c) ^ ((prow & 7) << 3))]);
            #pragma unroll
            for (int ef = 0; ef < 4; ++ef) {
                const int vrow = 16 * ef + lr;
                const short8 vb = *reinterpret_cast<const short8*>(
                    &Vt[vrow * 64 + ((8 * lg + 32 * c) ^ ((vrow & 7) << 3))]);
                o[ef] = __builtin_amdgcn_mfma_f32_16x16x32_bf16(pa, vb, o[ef], 0, 0, 0);
            }
        }
    }

    const int b = bh / H_, h = bh % H_;
    #pragma unroll
    for (int r = 0; r < 4; ++r) {
        const int t = qt * 64 + 16 * w + 4 * lg + r;
        const float inv = 1.0f / lsum[r];
        #pragma unroll
        for (int ef = 0; ef < 4; ++ef)
            aob[((size_t)t * B_ + b) * D_ + h * HD_ + 16 * ef + lr] =
                f2bf(o[ef][r] * inv);
    }
}

// ---------------------------------------------------------------------------
extern "C" void kernel_launch(void* const* d_in, const int* in_sizes, int n_in,
                              void* d_out, int out_size, void* d_ws, size_t ws_size,
                              hipStream_t stream)
{
    const float* query = (const float*)d_in[0];
    const float* keyi  = (const float*)d_in[1];
    const float* value = (const float*)d_in[2];
    const int*   lsp   = (const int*)  d_in[3];
    const float* Wq  = (const float*)d_in[4],  *bq  = (const float*)d_in[5];
    const float* Wk  = (const float*)d_in[6],  *bk  = (const float*)d_in[7];
    const float* Wv  = (const float*)d_in[8],  *bv  = (const float*)d_in[9];
    const float* Wqm = (const float*)d_in[10], *bqm = (const float*)d_in[11];
    const float* Wkm = (const float*)d_in[12], *bkm = (const float*)d_in[13];
    const float* Wvm = (const float*)d_in[14], *bvm = (const float*)d_in[15];
    const float* Wo  = (const float*)d_in[16], *bo  = (const float*)d_in[17];

    unsigned short* ws = (unsigned short*)d_ws;
    unsigned short* xb  = ws;                       // 3*XSZ
    unsigned short* wb  = xb + 3 * XSZ;             // 7*WSZ
    unsigned short* qh  = wb + 7 * WSZ;             // XSZ
    unsigned short* kh  = qh + XSZ;                 // XSZ
    unsigned short* vt  = kh + XSZ;                 // XSZ
    unsigned short* aob = vt + XSZ;                 // XSZ

    dim3 gc_(512, 10);
    convert_kernel<<<gc_, 256, 0, stream>>>(query, keyi, value,
                                            Wq, Wk, Wv, Wqm, Wkm, Wvm, Wo, xb);

    dim3 g1(D_ / 128, M_ / 128, 3);   // (6, 64, 3)
    qkv_gemm<<<g1, 256, 0, stream>>>(xb, wb, lsp, bq, bk, bv, bqm, bkm, bvm,
                                     qh, kh, vt);

    dim3 g2(T_ / 64, BH_);            // (16, 96)
    attn_kernel_bf16<<<g2, 256, 0, stream>>>(qh, kh, vt, aob);

    dim3 g3(D_ / 128, M_ / 128);      // (6, 64)
    out_gemm<<<g3, 256, 0, stream>>>(aob, wb + 6 * WSZ, bo, (float*)d_out);
}